// Round 6
// baseline (138.947 us; speedup 1.0000x reference)
//
#include <hip/hip_runtime.h>
#include <cfloat>

#define NB 4096           // nodes per batch
#define FD 64             // feature dim
#define EPT 16            // elements per thread = NB / 256
#define LRELU_ALPHA 0.2f
#define CAND_CAP 256

__device__ __forceinline__ unsigned long long shfl_xor_u64(unsigned long long v, int m) {
    int lo = __shfl_xor((int)(unsigned int)(v & 0xFFFFFFFFull), m, 64);
    int hi = __shfl_xor((int)(unsigned int)(v >> 32), m, 64);
    return ((unsigned long long)(unsigned int)hi << 32) | (unsigned int)lo;
}

// Prep: blocks 0..31 pack pq[i] = (px,py,pz,|p|^2 fast) for 8192 nodes;
// block 32 computes Wa1 = W@a[:64], Wa2 = W@a[64:].
__global__ __launch_bounds__(256) void prep_kernel(
    const float* __restrict__ pos, const float* __restrict__ W,
    const float* __restrict__ a, float* __restrict__ wa,
    float4* __restrict__ pq)
{
    const int tid = threadIdx.x;
    if (blockIdx.x == 32) {
        if (tid < 128) {
            const float* av = a + ((tid >> 6) << 6);
            const int i = tid & 63;
            float s = 0.f;
            #pragma unroll
            for (int j = 0; j < FD; ++j) s = fmaf(W[i * FD + j], av[j], s);
            wa[tid] = s;
        }
        return;
    }
    const int i = blockIdx.x * 256 + tid;          // 0..8191
    const float px = pos[i * 3 + 0];
    const float py = pos[i * 3 + 1];
    const float pz = pos[i * 3 + 2];
    pq[i] = make_float4(px, py, pz, fmaf(pz, pz, fmaf(py, py, px * px)));
}

// Fused kNN select (exact, jax.lax.top_k stable order) + attention.
// Phase A uses a fast fma-contracted d2 screen (6 VALU/node) + slack; only
// ~25 candidates get the exact rn-op-order d2 -> exact (d2,idx) rank order.
__global__ __launch_bounds__(256) void gat_fused(
    const float* __restrict__ x, const float* __restrict__ pos,
    const float* __restrict__ W, const float* __restrict__ wa,
    const float4* __restrict__ pq,
    const float* __restrict__ Wp, const float* __restrict__ bp,
    const int* __restrict__ kptr, float* __restrict__ out)
{
    __shared__ unsigned long long upool[672];      // A: wmf[84]|cand[256]; B: xs[21][64]
    __shared__ float sWa1[FD], sWa2[FD];
    __shared__ float sTf;
    __shared__ unsigned int cnt;
    __shared__ int idx21[32];                      // rank 0 = dropped col 0
    __shared__ float aw[32];
    __shared__ float sf1;
    __shared__ float gs[FD];
    __shared__ float part[4][FD];

    float* wmf = (float*)upool;                    // 84 floats (phase A1)
    unsigned long long* cand = upool + 84;         // 256 entries (phase A2)
    float (*xs)[FD] = (float(*)[FD])upool;         // 21*64 floats (phase B)

    const int tid = threadIdx.x;
    const int lane = tid & 63, wave = tid >> 6;
    const int row = blockIdx.x;                    // b*4096 + n
    const int b = row >> 12, n = row & (NB - 1);
    const float* posb = pos + (size_t)b * NB * 3;
    const float4* pqb = pq + ((size_t)b << 12);

    if (tid == 0) cnt = 0;
    if (tid < 2 * FD) { if (tid < FD) sWa1[tid] = wa[tid]; else sWa2[tid - FD] = wa[tid]; }

    const float4 q = pqb[n];
    const float qx = q.x, qy = q.y, qz = q.z, sqnf = q.w;

    // fast screen: one dwordx4 + 6 VALU per node
    float fk[EPT];
    float fmin = FLT_MAX;
    #pragma unroll
    for (int t = 0; t < EPT; ++t) {
        const int m = t * 256 + tid;
        const float4 p = pqb[m];
        const float dot = fmaf(qx, p.x, fmaf(qy, p.y, qz * p.z));
        const float d2 = fmaf(-2.f, dot, sqnf + p.w);
        fk[t] = d2;
        fmin = fminf(fmin, d2);
    }

    // wave-level f32 bitonic sort of the 64 per-thread minima
    float v = fmin;
    #pragma unroll
    for (int kk2 = 2; kk2 <= 64; kk2 <<= 1) {
        #pragma unroll
        for (int j = kk2 >> 1; j > 0; j >>= 1) {
            const float o = __shfl_xor(v, j, 64);
            const bool keepMin = (((lane & j) == 0) == ((lane & kk2) == 0));
            v = keepMin ? fminf(v, o) : fmaxf(v, o);
        }
    }
    if (lane < 21) wmf[wave * 21 + lane] = v;
    __syncthreads();

    // 21st-smallest of the 256 thread-minima (tie-robust), then add slack.
    // Bound: it is >= the global 21st-smallest fast-d2; slack >> max
    // |fast - exact| rounding gap, so candidates ⊇ exact top-21.
    if (tid < 84) {
        const float xv = wmf[tid];
        int rlt = 0, rle = 0;
        for (int j = 0; j < 84; ++j) { rlt += (wmf[j] < xv); rle += (wmf[j] <= xv); }
        if (rlt <= 20 && rle > 20) sTf = xv;
    }
    __syncthreads();
    const float Tsl = sTf + 1e-2f + 1e-3f * fabsf(sTf);
    __syncthreads();                               // wmf dead before cand reuse

    // exact rn-op-order d2 (numpy-bit-identical) for screened candidates only
    const float sqn = __fadd_rn(__fadd_rn(__fmul_rn(qx, qx), __fmul_rn(qy, qy)),
                                __fmul_rn(qz, qz));
    #pragma unroll
    for (int t = 0; t < EPT; ++t) {
        if (fk[t] <= Tsl) {
            const int m = t * 256 + tid;
            const float px = posb[m * 3 + 0];
            const float py = posb[m * 3 + 1];
            const float pz = posb[m * 3 + 2];
            const float sqm = __fadd_rn(__fadd_rn(__fmul_rn(px, px), __fmul_rn(py, py)),
                                        __fmul_rn(pz, pz));
            const float dot = __fadd_rn(__fadd_rn(__fmul_rn(qx, px), __fmul_rn(qy, py)),
                                        __fmul_rn(qz, pz));
            const float d2 = __fsub_rn(__fadd_rn(sqn, sqm), __fmul_rn(2.0f, dot));
            const unsigned int u = __float_as_uint(d2);
            const unsigned int kk = u ^ ((unsigned int)((int)u >> 31) | 0x80000000u);
            const unsigned long long pk =
                ((unsigned long long)kk << 12) | (unsigned int)m;
            const unsigned int p = atomicAdd(&cnt, 1u);
            if (p < CAND_CAP) cand[p] = pk;
        }
    }
    __syncthreads();

    const int k = *kptr;                           // 20
    const int K1 = k + 1;
    const int cn = cnt < (unsigned)CAND_CAP ? (int)cnt : CAND_CAP;
    if (tid < cn) {
        const unsigned long long xv = cand[tid];
        int r = 0;
        for (int j = 0; j < cn; ++j) r += (cand[j] < xv);
        // rank 0 = dropped first column; ranks 1..k = neighbors, stable order
        if (r <= k) idx21[r] = (int)(xv & 0xFFFu);
    }
    __syncthreads();                               // cand dead after this

    // phase B: gather x rows (rank 0..k) into upool-as-xs
    for (int t = wave; t < K1; t += 4)
        xs[t][lane] = x[((size_t)((b << 12) + idx21[t]) << 6) + lane];
    __syncthreads();

    // dots: t=0 -> f1 (self row @ Wa1), t>=1 -> f2_t (@ Wa2); butterfly reduce
    for (int t = wave; t < K1; t += 4) {
        const float* wv = (t == 0) ? sWa1 : sWa2;
        float p = xs[t][lane] * wv[lane];
        #pragma unroll
        for (int off = 32; off > 0; off >>= 1) p += __shfl_down(p, off, 64);
        if (lane == 0) { if (t == 0) sf1 = p; else aw[t] = p; }
    }
    __syncthreads();

    if (tid == 0) {
        const float f1v = sf1;
        float mx = -FLT_MAX;
        for (int t = 1; t <= k; ++t) {
            float e = f1v + aw[t];
            e = e > 0.f ? e : LRELU_ALPHA * e;
            aw[t] = e;
            mx = fmaxf(mx, e);
        }
        float Z = 0.f;
        for (int t = 1; t <= k; ++t) Z += __expf(aw[t] - mx);
        const float rz = 1.0f / Z;
        for (int t = 1; t <= k; ++t) aw[t] = __expf(aw[t] - mx) * rz;
    }
    __syncthreads();

    // g = attn @ x
    float gp = 0.f;
    for (int t = 1 + wave; t <= k; t += 4)
        gp = fmaf(aw[t], xs[t][lane], gp);
    part[wave][lane] = gp;
    __syncthreads();
    if (tid < FD) gs[tid] = part[0][tid] + part[1][tid] + part[2][tid] + part[3][tid];
    __syncthreads();

    // h = g @ W — W from global (16 KB, L1/L2-hot, coalesced rows)
    float hp = 0.f;
    #pragma unroll
    for (int i = 0; i < 16; ++i) {
        const int kk = wave * 16 + i;
        hp = fmaf(gs[kk], W[kk * FD + lane], hp);
    }
    part[wave][lane] = hp;
    __syncthreads();

    if (tid < FD) {
        float h = part[0][tid] + part[1][tid] + part[2][tid] + part[3][tid];
        float pv = fmaf(qx, Wp[0 * FD + tid],
                   fmaf(qy, Wp[1 * FD + tid],
                   fmaf(qz, Wp[2 * FD + tid], bp[tid])));
        h += pv > 0.f ? pv : 0.f;
        out[((size_t)row << 6) + tid] = h > 0.f ? h : expm1f(h);
    }
}

extern "C" void kernel_launch(void* const* d_in, const int* in_sizes, int n_in,
                              void* d_out, int out_size, void* d_ws, size_t ws_size,
                              hipStream_t stream) {
    const float* x   = (const float*)d_in[0];
    const float* pos = (const float*)d_in[1];
    const float* W   = (const float*)d_in[2];
    const float* a   = (const float*)d_in[3];
    const float* Wp  = (const float*)d_in[4];
    const float* bp  = (const float*)d_in[5];
    const int*   kp  = (const int*)d_in[6];
    float*  wa  = (float*)d_ws;                    // 128 floats (512 B, 16B-aligned)
    float4* pq  = (float4*)((char*)d_ws + 512);    // 8192 float4 = 128 KB
    float*  out = (float*)d_out;

    prep_kernel<<<33, 256, 0, stream>>>(pos, W, a, wa, pq);
    gat_fused<<<8192, 256, 0, stream>>>(x, pos, W, wa, pq, Wp, bp, kp, out);
}

// Round 7
// 111.687 us; speedup vs baseline: 1.2441x; 1.2441x over previous
//
#include <hip/hip_runtime.h>
#include <cfloat>

#define NB 4096           // nodes per batch
#define FD 64             // feature dim
#define EPT 16            // consecutive nodes per thread
#define QPB 4             // queries per block (one per wave)
#define LRELU_ALPHA 0.2f
#define CCAP 128          // per-query candidate cap (E[cands] ~ 26)

// Tiny precompute: Wa1 = W@a[:64], Wa2 = W@a[64:]  (block-invariant)
__global__ void wa_kernel(const float* __restrict__ W, const float* __restrict__ a,
                          float* __restrict__ wa) {
    const int t = threadIdx.x;            // 0..127
    const float* av = a + ((t >> 6) << 6);
    const int i = t & 63;
    float s = 0.f;
    #pragma unroll
    for (int j = 0; j < FD; ++j) s = fmaf(W[i * FD + j], av[j], s);
    wa[t] = s;
}

// 4 queries per block. One shared node stream serves all 4 screens (4x load
// amortization); per-query selection = 1 wave-private bitonic of 64 disjoint-
// group minima (T = sorted[k] is a provable screen bound); exact rn-order d2
// only for ~25 candidates -> neighbor set bit-identical to jax.lax.top_k.
// Phase B is wave-private (no barriers).
__global__ __launch_bounds__(256) void gat_fused(
    const float* __restrict__ x, const float* __restrict__ pos,
    const float* __restrict__ W, const float* __restrict__ wa,
    const float* __restrict__ Wp, const float* __restrict__ bp,
    const int* __restrict__ kptr, float* __restrict__ out)
{
    __shared__ unsigned long long upool[QPB * CCAP];   // 4 KB: tmin | cand overlay
    __shared__ float4 sq[QPB];                         // qx,qy,qz,|q|^2(rn)
    __shared__ float sT[QPB];
    __shared__ unsigned int cnt[QPB];
    __shared__ int idx21[QPB][64];

    float* tmin = (float*)upool;                       // QPB*256 floats (phase A1)
    unsigned long long (*cand)[CCAP] = (unsigned long long(*)[CCAP])upool;

    const int tid = threadIdx.x;
    const int lane = tid & 63, wave = tid >> 6;
    const int qbase = blockIdx.x * QPB;                // global row of query 0
    const int b = qbase >> 12;                         // 4096%QPB==0 -> same batch
    const float* posb = pos + (size_t)b * NB * 3;
    const int k = *kptr;                               // 20

    if (tid < QPB) {
        const int nq = (qbase + tid) & (NB - 1);
        const float ax = posb[nq * 3 + 0], ay = posb[nq * 3 + 1], az = posb[nq * 3 + 2];
        const float sr = __fadd_rn(__fadd_rn(__fmul_rn(ax, ax), __fmul_rn(ay, ay)),
                                   __fmul_rn(az, az));
        sq[tid] = make_float4(ax, ay, az, sr);
        cnt[tid] = 0;
    }
    __syncthreads();                                   // B1

    const float4 q0 = sq[0], q1 = sq[1], q2 = sq[2], q3 = sq[3];

    // pass 1: fast screen; per-thread min per query over 16 consecutive nodes
    const float4* p4 = (const float4*)posb;
    float f0 = FLT_MAX, f1m = FLT_MAX, f2m = FLT_MAX, f3m = FLT_MAX;
    #pragma unroll
    for (int c = 0; c < 4; ++c) {
        const float4 a0 = p4[tid * 12 + c * 3 + 0];
        const float4 a1 = p4[tid * 12 + c * 3 + 1];
        const float4 a2 = p4[tid * 12 + c * 3 + 2];
        const float pxs[4] = {a0.x, a0.w, a1.z, a2.y};
        const float pys[4] = {a0.y, a1.x, a1.w, a2.z};
        const float pzs[4] = {a0.z, a1.y, a2.x, a2.w};
        #pragma unroll
        for (int j = 0; j < 4; ++j) {
            const float px = pxs[j], py = pys[j], pz = pzs[j];
            const float sm = fmaf(pz, pz, fmaf(py, py, px * px));
            float d;
            d = fmaf(-2.f, fmaf(q0.x, px, fmaf(q0.y, py, q0.z * pz)), q0.w + sm);
            f0 = fminf(f0, d);
            d = fmaf(-2.f, fmaf(q1.x, px, fmaf(q1.y, py, q1.z * pz)), q1.w + sm);
            f1m = fminf(f1m, d);
            d = fmaf(-2.f, fmaf(q2.x, px, fmaf(q2.y, py, q2.z * pz)), q2.w + sm);
            f2m = fminf(f2m, d);
            d = fmaf(-2.f, fmaf(q3.x, px, fmaf(q3.y, py, q3.z * pz)), q3.w + sm);
            f3m = fminf(f3m, d);
        }
    }
    tmin[0 * 256 + tid] = f0;  tmin[1 * 256 + tid] = f1m;
    tmin[2 * 256 + tid] = f2m; tmin[3 * 256 + tid] = f3m;
    __syncthreads();                                   // B2

    // wave w sorts query w's 64 group-minima (groups of 64 disjoint nodes).
    // sorted[k] >= global (k+1)-th smallest: k+1 distinct groups each
    // contribute one element <= it.
    float v = fminf(fminf(tmin[wave * 256 + lane],       tmin[wave * 256 + 64 + lane]),
                    fminf(tmin[wave * 256 + 128 + lane], tmin[wave * 256 + 192 + lane]));
    #pragma unroll
    for (int kk2 = 2; kk2 <= 64; kk2 <<= 1) {
        #pragma unroll
        for (int j = kk2 >> 1; j > 0; j >>= 1) {
            const float o = __shfl_xor(v, j, 64);
            const bool keepMin = (((lane & j) == 0) == ((lane & kk2) == 0));
            v = keepMin ? fminf(v, o) : fmaxf(v, o);
        }
    }
    const float Tq = __shfl(v, k, 64);                 // ascending sort: lane k
    if (lane == 0) sT[wave] = Tq;
    __syncthreads();                                   // B3 (guards tmin->cand)

    // slack >> 2x max |fast-exact| rounding gap -> candidates ⊇ exact top-(k+1)
    const float Ts0 = sT[0] + 1e-2f + 1e-3f * fabsf(sT[0]);
    const float Ts1 = sT[1] + 1e-2f + 1e-3f * fabsf(sT[1]);
    const float Ts2 = sT[2] + 1e-2f + 1e-3f * fabsf(sT[2]);
    const float Ts3 = sT[3] + 1e-2f + 1e-3f * fabsf(sT[3]);

    // pass 2: re-screen fast; exact rn-order d2 (numpy-bit-identical) on take
    #pragma unroll
    for (int c = 0; c < 4; ++c) {
        const float4 a0 = p4[tid * 12 + c * 3 + 0];
        const float4 a1 = p4[tid * 12 + c * 3 + 1];
        const float4 a2 = p4[tid * 12 + c * 3 + 2];
        const float pxs[4] = {a0.x, a0.w, a1.z, a2.y};
        const float pys[4] = {a0.y, a1.x, a1.w, a2.z};
        const float pzs[4] = {a0.z, a1.y, a2.x, a2.w};
        #pragma unroll
        for (int j = 0; j < 4; ++j) {
            const float px = pxs[j], py = pys[j], pz = pzs[j];
            const float sm = fmaf(pz, pz, fmaf(py, py, px * px));
            const int m = tid * EPT + c * 4 + j;
            #pragma unroll
            for (int q = 0; q < QPB; ++q) {
                const float4 qq = (q == 0) ? q0 : (q == 1) ? q1 : (q == 2) ? q2 : q3;
                const float Tsl = (q == 0) ? Ts0 : (q == 1) ? Ts1 : (q == 2) ? Ts2 : Ts3;
                const float d = fmaf(-2.f, fmaf(qq.x, px, fmaf(qq.y, py, qq.z * pz)),
                                     qq.w + sm);
                if (d <= Tsl) {
                    const float sqm = __fadd_rn(__fadd_rn(__fmul_rn(px, px),
                                                          __fmul_rn(py, py)),
                                                __fmul_rn(pz, pz));
                    const float dot = __fadd_rn(__fadd_rn(__fmul_rn(qq.x, px),
                                                          __fmul_rn(qq.y, py)),
                                                __fmul_rn(qq.z, pz));
                    const float d2 = __fsub_rn(__fadd_rn(qq.w, sqm),
                                               __fmul_rn(2.0f, dot));
                    const unsigned int u = __float_as_uint(d2);
                    const unsigned int kk = u ^ ((unsigned int)((int)u >> 31) | 0x80000000u);
                    const unsigned long long pk =
                        ((unsigned long long)kk << 12) | (unsigned int)m;
                    const unsigned int p = atomicAdd(&cnt[q], 1u);
                    if (p < CCAP) cand[q][p] = pk;
                }
            }
        }
    }
    __syncthreads();                                   // B4 — last barrier

    // rank & select (wave w, query w): rank 0 = dropped col 0; 1..k = neighbors
    const int cn0 = (int)cnt[wave];
    const int cn = cn0 < CCAP ? cn0 : CCAP;
    for (int e = lane; e < cn; e += 64) {
        const unsigned long long xv = cand[wave][e];
        int r = 0;
        for (int j = 0; j < cn; ++j) r += (cand[wave][j] < xv);
        if (r <= k) idx21[wave][r] = (int)(xv & 0xFFFu);
    }
    // within-wave LDS RAW below: lockstep + compiler lgkmcnt, no barrier needed

    // phase B (wave-private): f1 = x[n]@Wa1; f2_t = x[nbr_t]@Wa2
    const int row = qbase + wave;
    const int nself = row & (NB - 1);
    const float4 qq = sq[wave];
    const float* xb = x + (((size_t)b << 12) << 6);
    const float wa1v = wa[lane], wa2v = wa[FD + lane];

    float p1 = xb[((size_t)nself << 6) + lane] * wa1v;
    #pragma unroll
    for (int off = 32; off > 0; off >>= 1) p1 += __shfl_xor(p1, off, 64);
    const float f1v = p1;

    float esc = 0.f;
    for (int t = 1; t <= k; ++t) {
        const int nb_ = idx21[wave][t];
        float pm = xb[((size_t)nb_ << 6) + lane] * wa2v;
        #pragma unroll
        for (int off = 32; off > 0; off >>= 1) pm += __shfl_xor(pm, off, 64);
        if (lane == t) esc = pm;
    }
    const bool valid = (lane >= 1 && lane <= k);
    float e = valid ? f1v + esc : -FLT_MAX;
    if (valid) e = e > 0.f ? e : LRELU_ALPHA * e;
    float mx = e;
    #pragma unroll
    for (int off = 32; off > 0; off >>= 1) mx = fmaxf(mx, __shfl_xor(mx, off, 64));
    const float ex = valid ? __expf(e - mx) : 0.f;
    float Z = ex;
    #pragma unroll
    for (int off = 32; off > 0; off >>= 1) Z += __shfl_xor(Z, off, 64);
    const float attn = ex / Z;                         // lane t holds attn_t

    // g = attn @ x  (neighbor rows, L1/L2-hot reload)
    float g = 0.f;
    for (int t = 1; t <= k; ++t) {
        const int nb_ = idx21[wave][t];
        const float xr = xb[((size_t)nb_ << 6) + lane];
        g = fmaf(__shfl(attn, t, 64), xr, g);
    }

    // h = g @ W  (shfl-broadcast; W rows coalesced, L1-hot)
    float h = 0.f;
    #pragma unroll 8
    for (int kk = 0; kk < FD; ++kk)
        h = fmaf(__shfl(g, kk, 64), W[kk * FD + lane], h);

    const float pv = fmaf(qq.x, Wp[0 * FD + lane],
                     fmaf(qq.y, Wp[1 * FD + lane],
                     fmaf(qq.z, Wp[2 * FD + lane], bp[lane])));
    h += pv > 0.f ? pv : 0.f;
    out[((size_t)row << 6) + lane] = h > 0.f ? h : expm1f(h);
}

extern "C" void kernel_launch(void* const* d_in, const int* in_sizes, int n_in,
                              void* d_out, int out_size, void* d_ws, size_t ws_size,
                              hipStream_t stream) {
    const float* x   = (const float*)d_in[0];
    const float* pos = (const float*)d_in[1];
    const float* W   = (const float*)d_in[2];
    const float* a   = (const float*)d_in[3];
    const float* Wp  = (const float*)d_in[4];
    const float* bp  = (const float*)d_in[5];
    const int*   kp  = (const int*)d_in[6];
    float* wa  = (float*)d_ws;                         // 128 floats
    float* out = (float*)d_out;

    wa_kernel<<<1, 128, 0, stream>>>(W, a, wa);
    gat_fused<<<(NB * 2) / QPB, 256, 0, stream>>>(x, pos, W, wa, Wp, bp, kp, out);
}